// Round 4
// baseline (278.838 us; speedup 1.0000x reference)
//
#include <hip/hip_runtime.h>

// Problem constants (from reference setup_inputs)
#define BATCH 16
#define NCLS 19
#define HW (1024 * 2048)            // elements per batch image
#define BLOCKS_PER_BATCH 128
#define NBLOCKS (BATCH * BLOCKS_PER_BATCH)          // 2048
#define THREADS 256
#define VEC_PER_BLOCK (HW / 4 / BLOCKS_PER_BATCH)   // 4096 int4 per block
#define ITERS (VEC_PER_BLOCK / THREADS)             // 16 int4 per thread
#define FLAG_MAGIC 0x5EC0DE77u      // != 0xAAAAAAAA poison, != 0

typedef int iv4 __attribute__((ext_vector_type(4)));  // clang vector: OK for nontemporal builtin

// Single fused kernel.
// Phase 1 (all 2048 blocks): presence bitmask over a contiguous 64 KiB chunk,
//   16 independent nontemporal int4 loads/thread for max MLP, block OR-reduce,
//   publish (mask, flag) with agent-scope atomics (cross-XCD visibility).
// Phase 2 (block 0 only): spin on all 2048 flags, OR-reduce to 16 batch masks,
//   stable BCE-with-logits over 304 logits, mean, write scalar.
__global__ __launch_bounds__(THREADS)
void fused_kernel(const int* __restrict__ targets, const float* __restrict__ preds,
                  unsigned* __restrict__ ws, float* __restrict__ out) {
    unsigned* masks = ws;             // [2048]
    unsigned* flags = ws + NBLOCKS;   // [2048]

    const int b   = blockIdx.x >> 7;              // / BLOCKS_PER_BATCH
    const int blk = blockIdx.x & (BLOCKS_PER_BATCH - 1);

    const iv4* tv = (const iv4*)targets
                  + (long long)b * (HW / 4)
                  + (long long)blk * VEC_PER_BLOCK
                  + threadIdx.x;

    iv4 v[ITERS];
    #pragma unroll
    for (int i = 0; i < ITERS; i++)
        v[i] = __builtin_nontemporal_load(&tv[i * THREADS]);   // 16 loads in flight

    unsigned m = 0;
    #pragma unroll
    for (int i = 0; i < ITERS; i++)
        m |= (1u << v[i].x) | (1u << v[i].y) | (1u << v[i].z) | (1u << v[i].w);

    // wave-64 OR reduction
    #pragma unroll
    for (int off = 32; off; off >>= 1) m |= __shfl_down(m, off);

    __shared__ unsigned sm[THREADS / 64];
    const int lane = threadIdx.x & 63;
    const int wave = threadIdx.x >> 6;
    if (lane == 0) sm[wave] = m;
    __syncthreads();
    if (threadIdx.x == 0) {
        unsigned r = sm[0] | sm[1] | sm[2] | sm[3];
        // mask first (relaxed), then flag with release: flag visibility implies mask visibility
        __hip_atomic_store(&masks[blockIdx.x], r, __ATOMIC_RELAXED, __HIP_MEMORY_SCOPE_AGENT);
        __hip_atomic_store(&flags[blockIdx.x], FLAG_MAGIC, __ATOMIC_RELEASE, __HIP_MEMORY_SCOPE_AGENT);
    }

    if (blockIdx.x != 0) return;   // block-uniform exit

    // ---- Phase 2: epilogue in block 0 ----
    const int tid = threadIdx.x;

    // thread tid polls indices [tid*8, tid*8+8) — all within batch tid>>4
    unsigned mm = 0;
    #pragma unroll
    for (int j = 0; j < 8; j++) {
        const int idx = tid * 8 + j;
        while (__hip_atomic_load(&flags[idx], __ATOMIC_ACQUIRE, __HIP_MEMORY_SCOPE_AGENT)
               != FLAG_MAGIC) {
            __builtin_amdgcn_s_sleep(1);
        }
        mm |= __hip_atomic_load(&masks[idx], __ATOMIC_RELAXED, __HIP_MEMORY_SCOPE_AGENT);
    }
    // reduce the 16 consecutive threads that share a batch
    #pragma unroll
    for (int off = 8; off; off >>= 1) mm |= __shfl_down(mm, off, 16);

    __shared__ unsigned bm[BATCH];
    if ((tid & 15) == 0) bm[tid >> 4] = mm;
    __syncthreads();

    // BCE with logits over 304 values, numerically stable:
    // -(t*logsig(x) + (1-t)*logsig(-x)) = max(x,0) - x*t + log1p(exp(-|x|))
    float s = 0.0f;
    for (int i = tid; i < BATCH * NCLS; i += THREADS) {
        const int bb = i / NCLS;
        const int c  = i % NCLS;
        const float x = preds[i];
        const float t = ((bm[bb] >> c) & 1u) ? 1.0f : 0.0f;
        s += fmaxf(x, 0.0f) - x * t + log1pf(expf(-fabsf(x)));
    }
    #pragma unroll
    for (int off = 32; off; off >>= 1) s += __shfl_down(s, off);

    __shared__ float red[THREADS / 64];
    if (lane == 0) red[wave] = s;
    __syncthreads();
    if (tid == 0)
        out[0] = (red[0] + red[1] + red[2] + red[3]) * (1.0f / (float)(BATCH * NCLS));
}

extern "C" void kernel_launch(void* const* d_in, const int* in_sizes, int n_in,
                              void* d_out, int out_size, void* d_ws, size_t ws_size,
                              hipStream_t stream) {
    const float* preds   = (const float*)d_in[0];   // [16, 19] fp32 logits
    const int*   targets = (const int*)d_in[1];     // [16, 1024, 2048] int32
    unsigned*    ws      = (unsigned*)d_ws;         // 2048 masks + 2048 flags = 16 KB
    float*       out     = (float*)d_out;           // scalar fp32

    fused_kernel<<<NBLOCKS, THREADS, 0, stream>>>(targets, preds, ws, out);
}

// Round 5
// 181.855 us; speedup vs baseline: 1.5333x; 1.5333x over previous
//
#include <hip/hip_runtime.h>

// Problem constants (from reference setup_inputs)
#define BATCH 16
#define NCLS 19
#define HW (1024 * 2048)            // elements per batch image
#define BLOCKS_PER_BATCH 128
#define THREADS 256
#define VEC_PER_BLOCK (HW / 4 / BLOCKS_PER_BATCH)   // 4096 int4 per block
#define ITERS (VEC_PER_BLOCK / THREADS)             // 16 int4 per thread

typedef int iv4 __attribute__((ext_vector_type(4)));  // clang vector: OK for nontemporal builtin

// Kernel 1: per-block class-presence bitmask over a contiguous chunk of targets.
// 2048 blocks x 256 thr = 8192 waves = full device wave capacity.
// 16 independent nontemporal int4 loads per thread for max memory-level
// parallelism. One plain partial-mask store per block; visibility to kernel 2
// is guaranteed by the kernel launch boundary (no in-kernel cross-XCD sync —
// R4 measured that at +100 us of wbl2/inv traffic).
__global__ __launch_bounds__(THREADS)
void presence_kernel(const int* __restrict__ targets, unsigned* __restrict__ partial) {
    const int b   = blockIdx.x >> 7;          // / BLOCKS_PER_BATCH
    const int blk = blockIdx.x & (BLOCKS_PER_BATCH - 1);

    const iv4* tv = (const iv4*)targets
                  + (long long)b * (HW / 4)
                  + (long long)blk * VEC_PER_BLOCK
                  + threadIdx.x;

    iv4 v[ITERS];
    #pragma unroll
    for (int i = 0; i < ITERS; i++)
        v[i] = __builtin_nontemporal_load(&tv[i * THREADS]);   // 16 loads in flight

    unsigned m = 0;
    #pragma unroll
    for (int i = 0; i < ITERS; i++)
        m |= (1u << v[i].x) | (1u << v[i].y) | (1u << v[i].z) | (1u << v[i].w);

    // wave-64 OR reduction
    #pragma unroll
    for (int off = 32; off; off >>= 1) m |= __shfl_down(m, off);

    __shared__ unsigned sm[THREADS / 64];
    const int lane = threadIdx.x & 63;
    const int wave = threadIdx.x >> 6;
    if (lane == 0) sm[wave] = m;
    __syncthreads();
    if (threadIdx.x == 0) {
        partial[blockIdx.x] = sm[0] | sm[1] | sm[2] | sm[3];  // unconditional -> no ws init
    }
}

// Kernel 2: single block, 256 threads. OR-reduce 2048 partials -> 16 batch
// masks, then stable BCE-with-logits over the 304 logits, mean, write scalar.
__global__ __launch_bounds__(256)
void loss_kernel(const float* __restrict__ preds, const unsigned* __restrict__ partial,
                 float* __restrict__ out) {
    __shared__ unsigned bm[BATCH];
    __shared__ float red[4];

    const int tid  = threadIdx.x;       // 0..255
    const int lane = tid & 63;
    const int wave = tid >> 6;

    // Reduce 2048 partials: 16 threads per batch, 8 loads each.
    {
        const int b = tid >> 4;         // 0..15
        const int j = tid & 15;
        unsigned m = 0;
        #pragma unroll
        for (int k = 0; k < BLOCKS_PER_BATCH / 16; k++)
            m |= partial[b * BLOCKS_PER_BATCH + j + 16 * k];
        #pragma unroll
        for (int off = 8; off; off >>= 1) m |= __shfl_down(m, off, 16);
        if (j == 0) bm[b] = m;
    }
    __syncthreads();

    float v = 0.0f;
    for (int i = tid; i < BATCH * NCLS; i += 256) {
        const int b = i / NCLS;
        const int c = i % NCLS;
        const float x = preds[i];
        const float t = ((bm[b] >> c) & 1u) ? 1.0f : 0.0f;
        // BCE with logits, numerically stable:
        // -(t*logsig(x) + (1-t)*logsig(-x)) = max(x,0) - x*t + log1p(exp(-|x|))
        v += fmaxf(x, 0.0f) - x * t + log1pf(expf(-fabsf(x)));
    }

    // wave-64 sum reduction
    #pragma unroll
    for (int off = 32; off; off >>= 1) v += __shfl_down(v, off);

    if (lane == 0) red[wave] = v;
    __syncthreads();
    if (tid == 0)
        out[0] = (red[0] + red[1] + red[2] + red[3]) * (1.0f / (float)(BATCH * NCLS));
}

extern "C" void kernel_launch(void* const* d_in, const int* in_sizes, int n_in,
                              void* d_out, int out_size, void* d_ws, size_t ws_size,
                              hipStream_t stream) {
    const float* preds   = (const float*)d_in[0];   // [16, 19] fp32 logits
    const int*   targets = (const int*)d_in[1];     // [16, 1024, 2048] int32
    unsigned*    partial = (unsigned*)d_ws;         // 2048 uints = 8 KB
    float*       out     = (float*)d_out;           // scalar fp32

    presence_kernel<<<BATCH * BLOCKS_PER_BATCH, THREADS, 0, stream>>>(targets, partial);
    loss_kernel<<<1, 256, 0, stream>>>(preds, partial, out);
}